// Round 1
// baseline (420.729 us; speedup 1.0000x reference)
//
#include <hip/hip_runtime.h>
#include <cmath>

#define B_   128
#define L_   256
#define HID_ 768
#define HID2_ 1536
#define CDIM_ 192
#define SDIM_ 128
#define NPROJ_ 128
#define FDIM_ 321
#define BIGV 1000000000.0f

// ---------------------------------------------------------------------------
// Kernel A: per-batch masked means + cls -> rep[b][0:768]=cls, [768:1536]=m0-m1
// grid = B*3 blocks of 256 threads (each block: one b, 256 h-columns)
// ---------------------------------------------------------------------------
__global__ __launch_bounds__(256) void stats_kernel(
    const float* __restrict__ H, const int* __restrict__ tt,
    const int* __restrict__ mm, float* __restrict__ rep, int* __restrict__ mcnt)
{
    int b = blockIdx.x / 3;
    int chunk = blockIdx.x % 3;
    int tid = threadIdx.x;

    __shared__ float sf0[L_], sf1[L_];
    {
        int t = tt[b * L_ + tid];
        int mv = mm[b * L_ + tid];
        bool is0 = (t == 0) && (mv == 1);
        bool is1 = (t == 1) && (mv == 1);
        sf0[tid] = is0 ? 1.0f : 0.0f;
        sf1[tid] = is1 ? 1.0f : 0.0f;
        int n0 = __syncthreads_count(is0);
        int n1 = __syncthreads_count(is1);
        if (chunk == 0 && tid == 0) mcnt[b] = (n0 < n1) ? n0 : n1;

        int h = chunk * 256 + tid;
        const float* Hb = H + (size_t)b * L_ * HID_;
        float a0 = 0.f, a1 = 0.f;
        for (int l = 0; l < L_; ++l) {
            float x = Hb[(size_t)l * HID_ + h];
            a0 += x * sf0[l];
            a1 += x * sf1[l];
        }
        float m0 = a0 / fmaxf((float)n0, 1.0f);
        float m1 = a1 / fmaxf((float)n1, 1.0f);
        rep[(size_t)b * HID2_ + h] = Hb[h];             // cls = H[b,0,h]
        rep[(size_t)b * HID2_ + HID_ + h] = m0 - m1;
    }
}

// ---------------------------------------------------------------------------
// Kernel B: fused head: fused[b][0:192]=(rep@Wc.T+bc)*(1-g), [192:320]=(rep@Ws.T+bs)*g
// one wave per (b, o); grid = B*320/4 blocks of 256
// ---------------------------------------------------------------------------
__global__ __launch_bounds__(256) void head_kernel(
    const float* __restrict__ rep, const float* __restrict__ Wc,
    const float* __restrict__ bc, const float* __restrict__ Ws,
    const float* __restrict__ bs, const float* __restrict__ gate,
    float* __restrict__ fused)
{
    int w = blockIdx.x * 4 + (threadIdx.x >> 6);
    int lane = threadIdx.x & 63;
    int b = w / (CDIM_ + SDIM_);
    int o = w % (CDIM_ + SDIM_);
    bool isC = (o < CDIM_);
    const float4* wr = (const float4*)(isC ? (Wc + (size_t)o * HID2_)
                                           : (Ws + (size_t)(o - CDIM_) * HID2_));
    const float4* rp = (const float4*)(rep + (size_t)b * HID2_);
    float acc = 0.f;
#pragma unroll
    for (int u = 0; u < 6; ++u) {
        int k4 = lane + u * 64;
        float4 a = rp[k4];
        float4 ww = wr[k4];
        acc += a.x * ww.x + a.y * ww.y + a.z * ww.z + a.w * ww.w;
    }
    for (int off = 32; off; off >>= 1) acc += __shfl_xor(acc, off, 64);
    if (lane == 0) {
        float g = 1.0f / (1.0f + expf(-gate[0]));
        float bias = isC ? bc[o] : bs[o - CDIM_];
        float scale = isC ? (1.0f - g) : g;
        fused[(size_t)b * (CDIM_ + SDIM_) + o] = (acc + bias) * scale;
    }
}

// ---------------------------------------------------------------------------
// Kernel C: Pt[b][p][l] = sum_k H[b,l,k] * proj[p,k]   (fp32 vector GEMM)
// block tile: 64 l x 64 p x 32 k; 256 threads, 4x4 microtile
// grid = B * (L/64) * (NPROJ/64) = 128*4*2 = 1024
// ---------------------------------------------------------------------------
__global__ __launch_bounds__(256) void gemm_p(
    const float* __restrict__ H, const float* __restrict__ Pd,
    float* __restrict__ Pt)
{
    int bid = blockIdx.x;
    int pt = bid & 1;          // p tile (0..1)
    int lt = (bid >> 1) & 3;   // l tile (0..3)
    int b  = bid >> 3;

    const float* A  = H  + ((size_t)b * L_ + lt * 64) * HID_;  // 64 x 768
    const float* Bm = Pd + (size_t)pt * 64 * HID_;             // 64 x 768

    __shared__ float As[64][36];
    __shared__ float Bs[64][36];

    int tid = threadIdx.x;
    int tx = tid & 15;   // l quad
    int ty = tid >> 4;   // p quad

    float acc[4][4] = {}; // [p][l]

    for (int k0 = 0; k0 < HID_; k0 += 32) {
#pragma unroll
        for (int u = 0; u < 2; ++u) {
            int f = tid + u * 256;     // 0..511
            int row = f >> 3;
            int c4  = f & 7;
            float4 va = *(const float4*)(A  + (size_t)row * HID_ + k0 + c4 * 4);
            *(float4*)(&As[row][c4 * 4]) = va;
            float4 vb = *(const float4*)(Bm + (size_t)row * HID_ + k0 + c4 * 4);
            *(float4*)(&Bs[row][c4 * 4]) = vb;
        }
        __syncthreads();
#pragma unroll
        for (int k4 = 0; k4 < 8; ++k4) {
            float4 a4[4], b4[4];
#pragma unroll
            for (int i = 0; i < 4; ++i) a4[i] = *(const float4*)(&As[tx * 4 + i][k4 * 4]);
#pragma unroll
            for (int j = 0; j < 4; ++j) b4[j] = *(const float4*)(&Bs[ty * 4 + j][k4 * 4]);
#pragma unroll
            for (int j = 0; j < 4; ++j)
#pragma unroll
                for (int i = 0; i < 4; ++i)
                    acc[j][i] += a4[i].x * b4[j].x + a4[i].y * b4[j].y
                               + a4[i].z * b4[j].z + a4[i].w * b4[j].w;
        }
        __syncthreads();
    }

#pragma unroll
    for (int j = 0; j < 4; ++j) {
        float4 o = make_float4(acc[j][0], acc[j][1], acc[j][2], acc[j][3]);
        float* dst = Pt + ((size_t)b * NPROJ_ + pt * 64 + ty * 4 + j) * L_
                        + lt * 64 + tx * 4;
        *(float4*)dst = o;
    }
}

// ---------------------------------------------------------------------------
// Kernel D: per (b,p): bitonic-sort masked projections, masked |diff| mean
// one wave per (b,p); element i lives at register r=i>>6 of lane i&63
// ---------------------------------------------------------------------------
__device__ inline void bitonic256(float v[4], int lane)
{
    for (int k = 2; k <= 256; k <<= 1) {
        for (int j = k >> 1; j > 0; j >>= 1) {
            if (j >= 64) {
                int rj = j >> 6;
#pragma unroll
                for (int r = 0; r < 4; ++r) {
                    if ((r & rj) == 0) {
                        int i = (r << 6) | lane;
                        bool up = ((i & k) == 0);
                        float lo = fminf(v[r], v[r | rj]);
                        float hi = fmaxf(v[r], v[r | rj]);
                        v[r]      = up ? lo : hi;
                        v[r | rj] = up ? hi : lo;
                    }
                }
            } else {
#pragma unroll
                for (int r = 0; r < 4; ++r) {
                    int i = (r << 6) | lane;
                    float w = __shfl_xor(v[r], j, 64);
                    bool lower = ((lane & j) == 0);
                    bool up = ((i & k) == 0);
                    v[r] = (lower == up) ? fminf(v[r], w) : fmaxf(v[r], w);
                }
            }
        }
    }
}

__global__ __launch_bounds__(256) void ot_kernel(
    const float* __restrict__ Pt, const int* __restrict__ tt,
    const int* __restrict__ mm, const int* __restrict__ mcnt,
    float* __restrict__ dist)
{
    int w = blockIdx.x * 4 + (threadIdx.x >> 6);
    int lane = threadIdx.x & 63;
    int b = w >> 7;
    int p = w & (NPROJ_ - 1);

    float4 pv = *(const float4*)(Pt + ((size_t)(b * NPROJ_ + p)) * L_ + lane * 4);
    int4 t4 = *(const int4*)(tt + (size_t)b * L_ + lane * 4);
    int4 m4 = *(const int4*)(mm + (size_t)b * L_ + lane * 4);

    float pvals[4] = {pv.x, pv.y, pv.z, pv.w};
    int tv[4] = {t4.x, t4.y, t4.z, t4.w};
    int mv[4] = {m4.x, m4.y, m4.z, m4.w};

    float v0[4], v1[4];
#pragma unroll
    for (int r = 0; r < 4; ++r) {
        bool is0 = (tv[r] == 0) && (mv[r] == 1);
        bool is1 = (tv[r] == 1) && (mv[r] == 1);
        v0[r] = is0 ? pvals[r] : BIGV;
        v1[r] = is1 ? pvals[r] : BIGV;
    }

    bitonic256(v0, lane);
    bitonic256(v1, lane);

    int mc = mcnt[b];
    float s = 0.f;
#pragma unroll
    for (int r = 0; r < 4; ++r) {
        int i = (r << 6) | lane;
        if (i < mc) s += fabsf(v0[r] - v1[r]);
    }
    for (int off = 32; off; off >>= 1) s += __shfl_xor(s, off, 64);
    if (lane == 0) dist[b * NPROJ_ + p] = s / (float)((mc > 1) ? mc : 1);
}

// ---------------------------------------------------------------------------
// Kernel E: d_ot = max_p dist; layernorm(concat(fused, d_ot)); @ Wcls.T + bcls
// one wave per batch
// ---------------------------------------------------------------------------
__global__ __launch_bounds__(64) void final_kernel(
    const float* __restrict__ fused, const float* __restrict__ dist,
    const float* __restrict__ ln_g, const float* __restrict__ ln_b,
    const float* __restrict__ Wcls, const float* __restrict__ bcls,
    float* __restrict__ out)
{
    int b = blockIdx.x;
    int lane = threadIdx.x;

    float mx = fmaxf(dist[b * NPROJ_ + lane], dist[b * NPROJ_ + 64 + lane]);
    for (int off = 32; off; off >>= 1) mx = fmaxf(mx, __shfl_xor(mx, off, 64));

    float fv[6];
    float sum = 0.f, sq = 0.f;
#pragma unroll
    for (int u = 0; u < 6; ++u) {
        int j = lane + u * 64;
        float x = 0.f;
        if (j < CDIM_ + SDIM_) x = fused[(size_t)b * (CDIM_ + SDIM_) + j];
        else if (j == CDIM_ + SDIM_) x = mx;
        fv[u] = x;
        if (j < FDIM_) { sum += x; sq += x * x; }
    }
    for (int off = 32; off; off >>= 1) {
        sum += __shfl_xor(sum, off, 64);
        sq  += __shfl_xor(sq,  off, 64);
    }
    float mu = sum / (float)FDIM_;
    float var = sq / (float)FDIM_ - mu * mu;
    float inv = rsqrtf(var + 1e-5f);

    float d0 = 0.f, d1 = 0.f;
#pragma unroll
    for (int u = 0; u < 6; ++u) {
        int j = lane + u * 64;
        if (j < FDIM_) {
            float nx = (fv[u] - mu) * inv * ln_g[j] + ln_b[j];
            d0 += nx * Wcls[j];
            d1 += nx * Wcls[FDIM_ + j];
        }
    }
    for (int off = 32; off; off >>= 1) {
        d0 += __shfl_xor(d0, off, 64);
        d1 += __shfl_xor(d1, off, 64);
    }
    if (lane == 0) {
        out[b * 2 + 0] = d0 + bcls[0];
        out[b * 2 + 1] = d1 + bcls[1];
    }
}

// ---------------------------------------------------------------------------
extern "C" void kernel_launch(void* const* d_in, const int* in_sizes, int n_in,
                              void* d_out, int out_size, void* d_ws, size_t ws_size,
                              hipStream_t stream)
{
    const float* H    = (const float*)d_in[0];
    const int*   tt   = (const int*)d_in[1];
    const int*   mm   = (const int*)d_in[2];
    const float* Wc   = (const float*)d_in[3];
    const float* bc   = (const float*)d_in[4];
    const float* Ws   = (const float*)d_in[5];
    const float* bs   = (const float*)d_in[6];
    const float* gate = (const float*)d_in[7];
    const float* ln_g = (const float*)d_in[8];
    const float* ln_b = (const float*)d_in[9];
    const float* Wcls = (const float*)d_in[10];
    const float* bcls = (const float*)d_in[11];
    const float* Pd   = (const float*)d_in[12];
    float* out = (float*)d_out;

    float* ws = (float*)d_ws;
    float* Pt    = ws;                              // B*NPROJ*L   = 4194304
    float* rep   = Pt + (size_t)B_ * NPROJ_ * L_;   // B*1536      = 196608
    float* fused = rep + (size_t)B_ * HID2_;        // B*320       = 40960
    float* dist  = fused + (size_t)B_ * (CDIM_ + SDIM_); // B*128  = 16384
    int*   mcnt  = (int*)(dist + (size_t)B_ * NPROJ_);   // B

    stats_kernel<<<B_ * 3, 256, 0, stream>>>(H, tt, mm, rep, mcnt);
    head_kernel<<<B_ * (CDIM_ + SDIM_) / 4, 256, 0, stream>>>(rep, Wc, bc, Ws, bs, gate, fused);
    gemm_p<<<B_ * (L_ / 64) * (NPROJ_ / 64), 256, 0, stream>>>(H, Pd, Pt);
    ot_kernel<<<B_ * NPROJ_ / 4, 256, 0, stream>>>(Pt, tt, mm, mcnt, dist);
    final_kernel<<<B_, 64, 0, stream>>>(fused, dist, ln_g, ln_b, Wcls, bcls, out);
}

// Round 2
// 335.747 us; speedup vs baseline: 1.2531x; 1.2531x over previous
//
#include <hip/hip_runtime.h>
#include <cmath>

#define B_   128
#define L_   256
#define HID_ 768
#define HID2_ 1536
#define CDIM_ 192
#define SDIM_ 128
#define NPROJ_ 128
#define FDIM_ 321
#define BIGV 1000000000.0f

typedef __attribute__((ext_vector_type(8))) short bf16x8;
typedef __attribute__((ext_vector_type(4))) float f32x4;

__device__ inline unsigned short bf_hi_trunc(float x) {
    return (unsigned short)(__float_as_uint(x) >> 16);
}
__device__ inline float bf2f(unsigned short s) {
    return __uint_as_float(((unsigned int)s) << 16);
}
__device__ inline unsigned short f2bf_rne(float x) {
    unsigned int u = __float_as_uint(x);
    unsigned int r = (u + 0x7fff + ((u >> 16) & 1)) >> 16;
    return (unsigned short)r;
}

// ---------------------------------------------------------------------------
// Kernel A: per-batch masked means + cls -> rep[b][0:768]=cls, [768:1536]=m0-m1
// ---------------------------------------------------------------------------
__global__ __launch_bounds__(256) void stats_kernel(
    const float* __restrict__ H, const int* __restrict__ tt,
    const int* __restrict__ mm, float* __restrict__ rep, int* __restrict__ mcnt)
{
    int b = blockIdx.x / 3;
    int chunk = blockIdx.x % 3;
    int tid = threadIdx.x;

    __shared__ float sf0[L_], sf1[L_];
    int t = tt[b * L_ + tid];
    int mv = mm[b * L_ + tid];
    bool is0 = (t == 0) && (mv == 1);
    bool is1 = (t == 1) && (mv == 1);
    sf0[tid] = is0 ? 1.0f : 0.0f;
    sf1[tid] = is1 ? 1.0f : 0.0f;
    int n0 = __syncthreads_count(is0);
    int n1 = __syncthreads_count(is1);
    if (chunk == 0 && tid == 0) mcnt[b] = (n0 < n1) ? n0 : n1;

    int h = chunk * 256 + tid;
    const float* Hb = H + (size_t)b * L_ * HID_;
    float a0 = 0.f, a1 = 0.f;
    for (int l = 0; l < L_; ++l) {
        float x = Hb[(size_t)l * HID_ + h];
        a0 += x * sf0[l];
        a1 += x * sf1[l];
    }
    float m0 = a0 / fmaxf((float)n0, 1.0f);
    float m1 = a1 / fmaxf((float)n1, 1.0f);
    rep[(size_t)b * HID2_ + h] = Hb[h];
    rep[(size_t)b * HID2_ + HID_ + h] = m0 - m1;
}

// ---------------------------------------------------------------------------
// Kernel B: fused head
// ---------------------------------------------------------------------------
__global__ __launch_bounds__(256) void head_kernel(
    const float* __restrict__ rep, const float* __restrict__ Wc,
    const float* __restrict__ bc, const float* __restrict__ Ws,
    const float* __restrict__ bs, const float* __restrict__ gate,
    float* __restrict__ fused)
{
    int w = blockIdx.x * 4 + (threadIdx.x >> 6);
    int lane = threadIdx.x & 63;
    int b = w / (CDIM_ + SDIM_);
    int o = w % (CDIM_ + SDIM_);
    bool isC = (o < CDIM_);
    const float4* wr = (const float4*)(isC ? (Wc + (size_t)o * HID2_)
                                           : (Ws + (size_t)(o - CDIM_) * HID2_));
    const float4* rp = (const float4*)(rep + (size_t)b * HID2_);
    float acc = 0.f;
#pragma unroll
    for (int u = 0; u < 6; ++u) {
        int k4 = lane + u * 64;
        float4 a = rp[k4];
        float4 ww = wr[k4];
        acc += a.x * ww.x + a.y * ww.y + a.z * ww.z + a.w * ww.w;
    }
    for (int off = 32; off; off >>= 1) acc += __shfl_xor(acc, off, 64);
    if (lane == 0) {
        float g = 1.0f / (1.0f + expf(-gate[0]));
        float bias = isC ? bc[o] : bs[o - CDIM_];
        float scale = isC ? (1.0f - g) : g;
        fused[(size_t)b * (CDIM_ + SDIM_) + o] = (acc + bias) * scale;
    }
}

// ---------------------------------------------------------------------------
// Kernel C0: pre-convert proj_dirs (128x768 fp32) to bf16 hi/lo pair
// ---------------------------------------------------------------------------
__global__ __launch_bounds__(256) void conv_proj(
    const float* __restrict__ Pd, unsigned short* __restrict__ hi,
    unsigned short* __restrict__ lo)
{
    int i = blockIdx.x * 256 + threadIdx.x;   // float4 index, total 24576
    float4 v = ((const float4*)Pd)[i];
    ushort4 h, l;
    h.x = bf_hi_trunc(v.x); l.x = f2bf_rne(v.x - bf2f(h.x));
    h.y = bf_hi_trunc(v.y); l.y = f2bf_rne(v.y - bf2f(h.y));
    h.z = bf_hi_trunc(v.z); l.z = f2bf_rne(v.z - bf2f(h.z));
    h.w = bf_hi_trunc(v.w); l.w = f2bf_rne(v.w - bf2f(h.w));
    ((ushort4*)hi)[i] = h;
    ((ushort4*)lo)[i] = l;
}

// ---------------------------------------------------------------------------
// Kernel C: Pt[b][p][l] = sum_k H[b,l,k]*proj[p,k] via split-bf16 MFMA.
//   A operand = proj rows (M=p), B operand = H rows (N=l), both K-major.
//   acc ~= Ah*Bh + Ah*Bl + Al*Bh  (lo*lo dropped, ~2^-16 relative)
// block: 256 thr / 4 waves; tile 128p x 64l x K=768; grid = B*4 = 512
// wave w: p in [w*32, w*32+32), l in [0,64): 2x4 tiles of 16x16
// C/D layout: col(lane&15)=l, row((lane>>4)*4+reg)=p -> coalesced Pt stores
// ---------------------------------------------------------------------------
#define LDSROW 72   // bf16 units per LDS row: [0:32) hi | [32:64) lo | pad
__global__ __launch_bounds__(256) void gemm_mfma(
    const float* __restrict__ H, const unsigned short* __restrict__ Pjh,
    const unsigned short* __restrict__ Pjl, float* __restrict__ Pt)
{
    __shared__ unsigned short Ps[128 * LDSROW];
    __shared__ unsigned short Hs[64 * LDSROW];

    int tid = threadIdx.x;
    int w = tid >> 6;
    int lane = tid & 63;
    int c = lane & 15;
    int q = lane >> 4;

    int b = blockIdx.x >> 2;
    int lbase = (blockIdx.x & 3) * 64;

    const float* Hbase = H + ((size_t)(b * 256 + lbase)) * HID_;

    int hrow = tid >> 3;     // 0..31 ; +32 for second chunk
    int hc4  = tid & 7;      // float4 within 32-k row
    int prow = tid >> 2;     // 0..63 ; +64 for second chunk
    int pk8  = tid & 3;      // 8-bf16 group within 32-k row

    f32x4 acc[2][4] = {};

    float4 hreg[2];
    uint4  phreg[2], plreg[2];

    {   // prefetch k0 = 0
        hreg[0]  = *(const float4*)(Hbase + (size_t)hrow * HID_ + hc4 * 4);
        hreg[1]  = *(const float4*)(Hbase + (size_t)(hrow + 32) * HID_ + hc4 * 4);
        phreg[0] = *(const uint4*)(Pjh + (size_t)prow * HID_ + pk8 * 8);
        phreg[1] = *(const uint4*)(Pjh + (size_t)(prow + 64) * HID_ + pk8 * 8);
        plreg[0] = *(const uint4*)(Pjl + (size_t)prow * HID_ + pk8 * 8);
        plreg[1] = *(const uint4*)(Pjl + (size_t)(prow + 64) * HID_ + pk8 * 8);
    }

    for (int it = 0; it < 24; ++it) {
        if (it) __syncthreads();            // protect LDS from prev-iter readers
#pragma unroll
        for (int u = 0; u < 2; ++u) {       // H fp32 -> bf16 hi/lo -> LDS
            int row = hrow + u * 32;
            float4 v = hreg[u];
            ushort4 h, l;
            h.x = bf_hi_trunc(v.x); l.x = f2bf_rne(v.x - bf2f(h.x));
            h.y = bf_hi_trunc(v.y); l.y = f2bf_rne(v.y - bf2f(h.y));
            h.z = bf_hi_trunc(v.z); l.z = f2bf_rne(v.z - bf2f(h.z));
            h.w = bf_hi_trunc(v.w); l.w = f2bf_rne(v.w - bf2f(h.w));
            *(ushort4*)&Hs[row * LDSROW + hc4 * 4]      = h;
            *(ushort4*)&Hs[row * LDSROW + 32 + hc4 * 4] = l;
        }
#pragma unroll
        for (int u = 0; u < 2; ++u) {       // proj bf16 tiles -> LDS
            int row = prow + u * 64;
            *(uint4*)&Ps[row * LDSROW + pk8 * 8]      = phreg[u];
            *(uint4*)&Ps[row * LDSROW + 32 + pk8 * 8] = plreg[u];
        }
        if (it + 1 < 24) {                  // register double-buffer prefetch
            int k0 = (it + 1) * 32;
            hreg[0]  = *(const float4*)(Hbase + (size_t)hrow * HID_ + k0 + hc4 * 4);
            hreg[1]  = *(const float4*)(Hbase + (size_t)(hrow + 32) * HID_ + k0 + hc4 * 4);
            phreg[0] = *(const uint4*)(Pjh + (size_t)prow * HID_ + k0 + pk8 * 8);
            phreg[1] = *(const uint4*)(Pjh + (size_t)(prow + 64) * HID_ + k0 + pk8 * 8);
            plreg[0] = *(const uint4*)(Pjl + (size_t)prow * HID_ + k0 + pk8 * 8);
            plreg[1] = *(const uint4*)(Pjl + (size_t)(prow + 64) * HID_ + k0 + pk8 * 8);
        }
        __syncthreads();

        bf16x8 ah[2], al[2], bh[4], bl[4];
#pragma unroll
        for (int pt = 0; pt < 2; ++pt) {
            int p = w * 32 + pt * 16 + c;
            ah[pt] = *(const bf16x8*)&Ps[p * LDSROW + q * 8];
            al[pt] = *(const bf16x8*)&Ps[p * LDSROW + 32 + q * 8];
        }
#pragma unroll
        for (int lt = 0; lt < 4; ++lt) {
            int l = lt * 16 + c;
            bh[lt] = *(const bf16x8*)&Hs[l * LDSROW + q * 8];
            bl[lt] = *(const bf16x8*)&Hs[l * LDSROW + 32 + q * 8];
        }
#pragma unroll
        for (int pt = 0; pt < 2; ++pt)
#pragma unroll
        for (int lt = 0; lt < 4; ++lt) {
            acc[pt][lt] = __builtin_amdgcn_mfma_f32_16x16x32_bf16(ah[pt], bh[lt], acc[pt][lt], 0, 0, 0);
            acc[pt][lt] = __builtin_amdgcn_mfma_f32_16x16x32_bf16(ah[pt], bl[lt], acc[pt][lt], 0, 0, 0);
            acc[pt][lt] = __builtin_amdgcn_mfma_f32_16x16x32_bf16(al[pt], bh[lt], acc[pt][lt], 0, 0, 0);
        }
    }

#pragma unroll
    for (int pt = 0; pt < 2; ++pt)
#pragma unroll
    for (int lt = 0; lt < 4; ++lt)
#pragma unroll
    for (int r = 0; r < 4; ++r) {
        int p = w * 32 + pt * 16 + q * 4 + r;
        int l = lbase + lt * 16 + c;
        Pt[((size_t)(b * NPROJ_ + p)) * L_ + l] = acc[pt][lt][r];
    }
}

// ---------------------------------------------------------------------------
// Kernel D: per (b,p) bitonic sort + masked |diff| mean
// ---------------------------------------------------------------------------
__device__ inline void bitonic256(float v[4], int lane)
{
    for (int k = 2; k <= 256; k <<= 1) {
        for (int j = k >> 1; j > 0; j >>= 1) {
            if (j >= 64) {
                int rj = j >> 6;
#pragma unroll
                for (int r = 0; r < 4; ++r) {
                    if ((r & rj) == 0) {
                        int i = (r << 6) | lane;
                        bool up = ((i & k) == 0);
                        float lo = fminf(v[r], v[r | rj]);
                        float hi = fmaxf(v[r], v[r | rj]);
                        v[r]      = up ? lo : hi;
                        v[r | rj] = up ? hi : lo;
                    }
                }
            } else {
#pragma unroll
                for (int r = 0; r < 4; ++r) {
                    int i = (r << 6) | lane;
                    float w = __shfl_xor(v[r], j, 64);
                    bool lower = ((lane & j) == 0);
                    bool up = ((i & k) == 0);
                    v[r] = (lower == up) ? fminf(v[r], w) : fmaxf(v[r], w);
                }
            }
        }
    }
}

__global__ __launch_bounds__(256) void ot_kernel(
    const float* __restrict__ Pt, const int* __restrict__ tt,
    const int* __restrict__ mm, const int* __restrict__ mcnt,
    float* __restrict__ dist)
{
    int w = blockIdx.x * 4 + (threadIdx.x >> 6);
    int lane = threadIdx.x & 63;
    int b = w >> 7;
    int p = w & (NPROJ_ - 1);

    float4 pv = *(const float4*)(Pt + ((size_t)(b * NPROJ_ + p)) * L_ + lane * 4);
    int4 t4 = *(const int4*)(tt + (size_t)b * L_ + lane * 4);
    int4 m4 = *(const int4*)(mm + (size_t)b * L_ + lane * 4);

    float pvals[4] = {pv.x, pv.y, pv.z, pv.w};
    int tv[4] = {t4.x, t4.y, t4.z, t4.w};
    int mv[4] = {m4.x, m4.y, m4.z, m4.w};

    float v0[4], v1[4];
#pragma unroll
    for (int r = 0; r < 4; ++r) {
        bool is0 = (tv[r] == 0) && (mv[r] == 1);
        bool is1 = (tv[r] == 1) && (mv[r] == 1);
        v0[r] = is0 ? pvals[r] : BIGV;
        v1[r] = is1 ? pvals[r] : BIGV;
    }

    bitonic256(v0, lane);
    bitonic256(v1, lane);

    int mc = mcnt[b];
    float s = 0.f;
#pragma unroll
    for (int r = 0; r < 4; ++r) {
        int i = (r << 6) | lane;
        if (i < mc) s += fabsf(v0[r] - v1[r]);
    }
    for (int off = 32; off; off >>= 1) s += __shfl_xor(s, off, 64);
    if (lane == 0) dist[b * NPROJ_ + p] = s / (float)((mc > 1) ? mc : 1);
}

// ---------------------------------------------------------------------------
// Kernel E: max over p, layernorm, classifier
// ---------------------------------------------------------------------------
__global__ __launch_bounds__(64) void final_kernel(
    const float* __restrict__ fused, const float* __restrict__ dist,
    const float* __restrict__ ln_g, const float* __restrict__ ln_b,
    const float* __restrict__ Wcls, const float* __restrict__ bcls,
    float* __restrict__ out)
{
    int b = blockIdx.x;
    int lane = threadIdx.x;

    float mx = fmaxf(dist[b * NPROJ_ + lane], dist[b * NPROJ_ + 64 + lane]);
    for (int off = 32; off; off >>= 1) mx = fmaxf(mx, __shfl_xor(mx, off, 64));

    float fv[6];
    float sum = 0.f, sq = 0.f;
#pragma unroll
    for (int u = 0; u < 6; ++u) {
        int j = lane + u * 64;
        float x = 0.f;
        if (j < CDIM_ + SDIM_) x = fused[(size_t)b * (CDIM_ + SDIM_) + j];
        else if (j == CDIM_ + SDIM_) x = mx;
        fv[u] = x;
        if (j < FDIM_) { sum += x; sq += x * x; }
    }
    for (int off = 32; off; off >>= 1) {
        sum += __shfl_xor(sum, off, 64);
        sq  += __shfl_xor(sq,  off, 64);
    }
    float mu = sum / (float)FDIM_;
    float var = sq / (float)FDIM_ - mu * mu;
    float inv = rsqrtf(var + 1e-5f);

    float d0 = 0.f, d1 = 0.f;
#pragma unroll
    for (int u = 0; u < 6; ++u) {
        int j = lane + u * 64;
        if (j < FDIM_) {
            float nx = (fv[u] - mu) * inv * ln_g[j] + ln_b[j];
            d0 += nx * Wcls[j];
            d1 += nx * Wcls[FDIM_ + j];
        }
    }
    for (int off = 32; off; off >>= 1) {
        d0 += __shfl_xor(d0, off, 64);
        d1 += __shfl_xor(d1, off, 64);
    }
    if (lane == 0) {
        out[b * 2 + 0] = d0 + bcls[0];
        out[b * 2 + 1] = d1 + bcls[1];
    }
}

// ---------------------------------------------------------------------------
extern "C" void kernel_launch(void* const* d_in, const int* in_sizes, int n_in,
                              void* d_out, int out_size, void* d_ws, size_t ws_size,
                              hipStream_t stream)
{
    const float* H    = (const float*)d_in[0];
    const int*   tt   = (const int*)d_in[1];
    const int*   mm   = (const int*)d_in[2];
    const float* Wc   = (const float*)d_in[3];
    const float* bc   = (const float*)d_in[4];
    const float* Ws   = (const float*)d_in[5];
    const float* bs   = (const float*)d_in[6];
    const float* gate = (const float*)d_in[7];
    const float* ln_g = (const float*)d_in[8];
    const float* ln_b = (const float*)d_in[9];
    const float* Wcls = (const float*)d_in[10];
    const float* bcls = (const float*)d_in[11];
    const float* Pd   = (const float*)d_in[12];
    float* out = (float*)d_out;

    float* ws = (float*)d_ws;
    float* Pt    = ws;                                   // B*NPROJ*L = 4194304 fl
    float* rep   = Pt + (size_t)B_ * NPROJ_ * L_;        // B*1536
    float* fused = rep + (size_t)B_ * HID2_;             // B*320
    float* dist  = fused + (size_t)B_ * (CDIM_ + SDIM_); // B*128
    int*   mcnt  = (int*)(dist + (size_t)B_ * NPROJ_);   // B ints
    unsigned short* Pjh = (unsigned short*)(mcnt + B_);  // 98304 bf16
    unsigned short* Pjl = Pjh + (size_t)NPROJ_ * HID_;   // 98304 bf16

    conv_proj<<<NPROJ_ * HID_ / 4 / 256, 256, 0, stream>>>(Pd, Pjh, Pjl);
    stats_kernel<<<B_ * 3, 256, 0, stream>>>(H, tt, mm, rep, mcnt);
    head_kernel<<<B_ * (CDIM_ + SDIM_) / 4, 256, 0, stream>>>(rep, Wc, bc, Ws, bs, gate, fused);
    gemm_mfma<<<B_ * 4, 256, 0, stream>>>(H, Pjh, Pjl, Pt);
    ot_kernel<<<B_ * NPROJ_ / 4, 256, 0, stream>>>(Pt, tt, mm, mcnt, dist);
    final_kernel<<<B_, 64, 0, stream>>>(fused, dist, ln_g, ln_b, Wcls, bcls, out);
}

// Round 3
// 265.367 us; speedup vs baseline: 1.5855x; 1.2652x over previous
//
#include <hip/hip_runtime.h>
#include <cmath>

#define B_   128
#define L_   256
#define HID_ 768
#define HID2_ 1536
#define CDIM_ 192
#define SDIM_ 128
#define NPROJ_ 128
#define FDIM_ 321

typedef __attribute__((ext_vector_type(8))) short bf16x8;
typedef __attribute__((ext_vector_type(4))) float f32x4;

__device__ inline unsigned short bf_hi_trunc(float x) {
    return (unsigned short)(__float_as_uint(x) >> 16);
}
__device__ inline float bf2f(unsigned short s) {
    return __uint_as_float(((unsigned int)s) << 16);
}
__device__ inline unsigned short f2bf_rne(float x) {
    unsigned int u = __float_as_uint(x);
    unsigned int r = (u + 0x7fff + ((u >> 16) & 1)) >> 16;
    return (unsigned short)r;
}

// ---------------------------------------------------------------------------
// Kernel A1: partial masked sums. grid = B*4, 192 threads.
// part[(b*4+pr)][0:768]=sum f0*H, [768:1536]=sum f1*H  (over 64 l-rows)
// ---------------------------------------------------------------------------
__global__ __launch_bounds__(192) void stats_part(
    const float* __restrict__ H, const int* __restrict__ tt,
    const int* __restrict__ mm, float* __restrict__ part)
{
    int b  = blockIdx.x >> 2;
    int pr = blockIdx.x & 3;
    int tid = threadIdx.x;

    __shared__ float sf0[64], sf1[64];
    if (tid < 64) {
        int l = pr * 64 + tid;
        int t = tt[b * L_ + l];
        int mv = mm[b * L_ + l];
        sf0[tid] = (t == 0 && mv == 1) ? 1.f : 0.f;
        sf1[tid] = (t == 1 && mv == 1) ? 1.f : 0.f;
    }
    __syncthreads();

    const float* Hb = H + ((size_t)(b * L_ + pr * 64)) * HID_;
    float4 a0 = make_float4(0.f, 0.f, 0.f, 0.f);
    float4 a1 = make_float4(0.f, 0.f, 0.f, 0.f);
    for (int l = 0; l < 64; ++l) {
        float4 x = *(const float4*)(Hb + (size_t)l * HID_ + tid * 4);
        float f0 = sf0[l], f1 = sf1[l];
        a0.x += x.x * f0; a0.y += x.y * f0; a0.z += x.z * f0; a0.w += x.w * f0;
        a1.x += x.x * f1; a1.y += x.y * f1; a1.z += x.z * f1; a1.w += x.w * f1;
    }
    float* dst = part + ((size_t)(b * 4 + pr)) * HID2_;
    *(float4*)(dst + tid * 4) = a0;
    *(float4*)(dst + HID_ + tid * 4) = a1;
}

// ---------------------------------------------------------------------------
// Kernel A2: finalize rep. grid = B, 256 threads.
// ---------------------------------------------------------------------------
__global__ __launch_bounds__(256) void stats_fin(
    const float* __restrict__ H, const int* __restrict__ tt,
    const int* __restrict__ mm, const float* __restrict__ part,
    float* __restrict__ rep)
{
    int b = blockIdx.x;
    int tid = threadIdx.x;
    int t = tt[b * L_ + tid];
    int mv = mm[b * L_ + tid];
    int n0 = __syncthreads_count(t == 0 && mv == 1);
    int n1 = __syncthreads_count(t == 1 && mv == 1);
    float r0 = 1.f / fmaxf((float)n0, 1.f);
    float r1 = 1.f / fmaxf((float)n1, 1.f);

    const float* pp = part + (size_t)b * 4 * HID2_;
    for (int h = tid; h < HID_; h += 256) {
        float a0 = pp[h] + pp[HID2_ + h] + pp[2 * HID2_ + h] + pp[3 * HID2_ + h];
        float a1 = pp[HID_ + h] + pp[HID2_ + HID_ + h]
                 + pp[2 * HID2_ + HID_ + h] + pp[3 * HID2_ + HID_ + h];
        rep[(size_t)b * HID2_ + h] = H[(size_t)b * L_ * HID_ + h];
        rep[(size_t)b * HID2_ + HID_ + h] = a0 * r0 - a1 * r1;
    }
}

// ---------------------------------------------------------------------------
// Kernel B: fused head (unchanged)
// ---------------------------------------------------------------------------
__global__ __launch_bounds__(256) void head_kernel(
    const float* __restrict__ rep, const float* __restrict__ Wc,
    const float* __restrict__ bc, const float* __restrict__ Ws,
    const float* __restrict__ bs, const float* __restrict__ gate,
    float* __restrict__ fused)
{
    int w = blockIdx.x * 4 + (threadIdx.x >> 6);
    int lane = threadIdx.x & 63;
    int b = w / (CDIM_ + SDIM_);
    int o = w % (CDIM_ + SDIM_);
    bool isC = (o < CDIM_);
    const float4* wr = (const float4*)(isC ? (Wc + (size_t)o * HID2_)
                                           : (Ws + (size_t)(o - CDIM_) * HID2_));
    const float4* rp = (const float4*)(rep + (size_t)b * HID2_);
    float acc = 0.f;
#pragma unroll
    for (int u = 0; u < 6; ++u) {
        int k4 = lane + u * 64;
        float4 a = rp[k4];
        float4 ww = wr[k4];
        acc += a.x * ww.x + a.y * ww.y + a.z * ww.z + a.w * ww.w;
    }
    for (int off = 32; off; off >>= 1) acc += __shfl_xor(acc, off, 64);
    if (lane == 0) {
        float g = 1.0f / (1.0f + expf(-gate[0]));
        float bias = isC ? bc[o] : bs[o - CDIM_];
        float scale = isC ? (1.0f - g) : g;
        fused[(size_t)b * (CDIM_ + SDIM_) + o] = (acc + bias) * scale;
    }
}

// ---------------------------------------------------------------------------
// Kernel C0: pre-convert proj_dirs to bf16 hi/lo
// ---------------------------------------------------------------------------
__global__ __launch_bounds__(256) void conv_proj(
    const float* __restrict__ Pd, unsigned short* __restrict__ hi,
    unsigned short* __restrict__ lo)
{
    int i = blockIdx.x * 256 + threadIdx.x;
    float4 v = ((const float4*)Pd)[i];
    ushort4 h, l;
    h.x = bf_hi_trunc(v.x); l.x = f2bf_rne(v.x - bf2f(h.x));
    h.y = bf_hi_trunc(v.y); l.y = f2bf_rne(v.y - bf2f(h.y));
    h.z = bf_hi_trunc(v.z); l.z = f2bf_rne(v.z - bf2f(h.z));
    h.w = bf_hi_trunc(v.w); l.w = f2bf_rne(v.w - bf2f(h.w));
    ((ushort4*)hi)[i] = h;
    ((ushort4*)lo)[i] = l;
}

// ---------------------------------------------------------------------------
// Kernel C: split-bf16 MFMA GEMM with true LDS double-buffer (1 barrier/iter)
// tile 128p x 64l x K=768, grid = B*4, 256 threads
// ---------------------------------------------------------------------------
#define LDSROW 72
__global__ __launch_bounds__(256) void gemm_mfma(
    const float* __restrict__ H, const unsigned short* __restrict__ Pjh,
    const unsigned short* __restrict__ Pjl, float* __restrict__ Pt)
{
    __shared__ unsigned short Ps[2][128 * LDSROW];
    __shared__ unsigned short Hs[2][64 * LDSROW];

    int tid = threadIdx.x;
    int w = tid >> 6;
    int lane = tid & 63;
    int c = lane & 15;
    int q = lane >> 4;

    int b = blockIdx.x >> 2;
    int lbase = (blockIdx.x & 3) * 64;

    const float* Hbase = H + ((size_t)(b * L_ + lbase)) * HID_;

    int hrow = tid >> 3;     // 0..31 (+32)
    int hc4  = tid & 7;
    int prow = tid >> 2;     // 0..63 (+64)
    int pk8  = tid & 3;

    f32x4 acc[2][4] = {};

    float4 hreg[2];
    uint4  phreg[2], plreg[2];

    // stage iter 0 into buffer 0
    hreg[0]  = *(const float4*)(Hbase + (size_t)hrow * HID_ + hc4 * 4);
    hreg[1]  = *(const float4*)(Hbase + (size_t)(hrow + 32) * HID_ + hc4 * 4);
    phreg[0] = *(const uint4*)(Pjh + (size_t)prow * HID_ + pk8 * 8);
    phreg[1] = *(const uint4*)(Pjh + (size_t)(prow + 64) * HID_ + pk8 * 8);
    plreg[0] = *(const uint4*)(Pjl + (size_t)prow * HID_ + pk8 * 8);
    plreg[1] = *(const uint4*)(Pjl + (size_t)(prow + 64) * HID_ + pk8 * 8);
#pragma unroll
    for (int u = 0; u < 2; ++u) {
        int row = hrow + u * 32;
        float4 v = hreg[u];
        ushort4 h, l;
        h.x = bf_hi_trunc(v.x); l.x = f2bf_rne(v.x - bf2f(h.x));
        h.y = bf_hi_trunc(v.y); l.y = f2bf_rne(v.y - bf2f(h.y));
        h.z = bf_hi_trunc(v.z); l.z = f2bf_rne(v.z - bf2f(h.z));
        h.w = bf_hi_trunc(v.w); l.w = f2bf_rne(v.w - bf2f(h.w));
        *(ushort4*)&Hs[0][row * LDSROW + hc4 * 4]      = h;
        *(ushort4*)&Hs[0][row * LDSROW + 32 + hc4 * 4] = l;
    }
#pragma unroll
    for (int u = 0; u < 2; ++u) {
        int row = prow + u * 64;
        *(uint4*)&Ps[0][row * LDSROW + pk8 * 8]      = phreg[u];
        *(uint4*)&Ps[0][row * LDSROW + 32 + pk8 * 8] = plreg[u];
    }
    __syncthreads();

    for (int it = 0; it < 24; ++it) {
        int cur = it & 1;
        int nxt = cur ^ 1;

        if (it + 1 < 24) {          // prefetch next K-chunk (overlaps MFMA below)
            int k0 = (it + 1) * 32;
            hreg[0]  = *(const float4*)(Hbase + (size_t)hrow * HID_ + k0 + hc4 * 4);
            hreg[1]  = *(const float4*)(Hbase + (size_t)(hrow + 32) * HID_ + k0 + hc4 * 4);
            phreg[0] = *(const uint4*)(Pjh + (size_t)prow * HID_ + k0 + pk8 * 8);
            phreg[1] = *(const uint4*)(Pjh + (size_t)(prow + 64) * HID_ + k0 + pk8 * 8);
            plreg[0] = *(const uint4*)(Pjl + (size_t)prow * HID_ + k0 + pk8 * 8);
            plreg[1] = *(const uint4*)(Pjl + (size_t)(prow + 64) * HID_ + k0 + pk8 * 8);
        }

        bf16x8 ah[2], al[2], bh[4], bl[4];
#pragma unroll
        for (int pt = 0; pt < 2; ++pt) {
            int p = w * 32 + pt * 16 + c;
            ah[pt] = *(const bf16x8*)&Ps[cur][p * LDSROW + q * 8];
            al[pt] = *(const bf16x8*)&Ps[cur][p * LDSROW + 32 + q * 8];
        }
#pragma unroll
        for (int lt = 0; lt < 4; ++lt) {
            int l = lt * 16 + c;
            bh[lt] = *(const bf16x8*)&Hs[cur][l * LDSROW + q * 8];
            bl[lt] = *(const bf16x8*)&Hs[cur][l * LDSROW + 32 + q * 8];
        }
#pragma unroll
        for (int pt = 0; pt < 2; ++pt)
#pragma unroll
        for (int lt = 0; lt < 4; ++lt) {
            acc[pt][lt] = __builtin_amdgcn_mfma_f32_16x16x32_bf16(ah[pt], bh[lt], acc[pt][lt], 0, 0, 0);
            acc[pt][lt] = __builtin_amdgcn_mfma_f32_16x16x32_bf16(ah[pt], bl[lt], acc[pt][lt], 0, 0, 0);
            acc[pt][lt] = __builtin_amdgcn_mfma_f32_16x16x32_bf16(al[pt], bh[lt], acc[pt][lt], 0, 0, 0);
        }

        if (it + 1 < 24) {          // convert + stage into the other buffer
#pragma unroll
            for (int u = 0; u < 2; ++u) {
                int row = hrow + u * 32;
                float4 v = hreg[u];
                ushort4 h, l;
                h.x = bf_hi_trunc(v.x); l.x = f2bf_rne(v.x - bf2f(h.x));
                h.y = bf_hi_trunc(v.y); l.y = f2bf_rne(v.y - bf2f(h.y));
                h.z = bf_hi_trunc(v.z); l.z = f2bf_rne(v.z - bf2f(h.z));
                h.w = bf_hi_trunc(v.w); l.w = f2bf_rne(v.w - bf2f(h.w));
                *(ushort4*)&Hs[nxt][row * LDSROW + hc4 * 4]      = h;
                *(ushort4*)&Hs[nxt][row * LDSROW + 32 + hc4 * 4] = l;
            }
#pragma unroll
            for (int u = 0; u < 2; ++u) {
                int row = prow + u * 64;
                *(uint4*)&Ps[nxt][row * LDSROW + pk8 * 8]      = phreg[u];
                *(uint4*)&Ps[nxt][row * LDSROW + 32 + pk8 * 8] = plreg[u];
            }
        }
        __syncthreads();
    }

#pragma unroll
    for (int pt = 0; pt < 2; ++pt)
#pragma unroll
    for (int lt = 0; lt < 4; ++lt)
#pragma unroll
    for (int r = 0; r < 4; ++r) {
        int p = w * 32 + pt * 16 + q * 4 + r;
        int l = lbase + lt * 16 + c;
        Pt[((size_t)(b * NPROJ_ + p)) * L_ + l] = acc[pt][lt][r];
    }
}

// ---------------------------------------------------------------------------
// Kernel D: merged-sort W1 distance.
// key = sortable_u32(P) with label in 2 LSBs; ONE bitonic sort of 256;
// packed prefix counts; contribution t_i*(w_{i-1}-w_i) (Abel summation of
// integral |min(F0,m)-min(F1,m)| dt).
// ---------------------------------------------------------------------------
__device__ inline void bitonic256_u32(unsigned v[4], int lane)
{
    for (int k = 2; k <= 256; k <<= 1) {
        for (int j = k >> 1; j > 0; j >>= 1) {
            if (j >= 64) {
                int rj = j >> 6;
#pragma unroll
                for (int r = 0; r < 4; ++r) {
                    if ((r & rj) == 0) {
                        int i = (r << 6) | lane;
                        bool up = ((i & k) == 0);
                        unsigned lo = min(v[r], v[r | rj]);
                        unsigned hi = max(v[r], v[r | rj]);
                        v[r]      = up ? lo : hi;
                        v[r | rj] = up ? hi : lo;
                    }
                }
            } else {
#pragma unroll
                for (int r = 0; r < 4; ++r) {
                    int i = (r << 6) | lane;
                    unsigned w = (unsigned)__shfl_xor((int)v[r], j, 64);
                    bool lower = ((lane & j) == 0);
                    bool up = ((i & k) == 0);
                    v[r] = (lower == up) ? min(v[r], w) : max(v[r], w);
                }
            }
        }
    }
}

__global__ __launch_bounds__(256) void ot_kernel(
    const float* __restrict__ Pt, const int* __restrict__ tt,
    const int* __restrict__ mm, float* __restrict__ dist)
{
    int w = blockIdx.x * 4 + (threadIdx.x >> 6);
    int lane = threadIdx.x & 63;
    int b = w >> 7;
    int p = w & (NPROJ_ - 1);

    float4 pv = *(const float4*)(Pt + ((size_t)(b * NPROJ_ + p)) * L_ + lane * 4);
    int4 t4 = *(const int4*)(tt + (size_t)b * L_ + lane * 4);
    int4 m4 = *(const int4*)(mm + (size_t)b * L_ + lane * 4);

    float pvals[4] = {pv.x, pv.y, pv.z, pv.w};
    int tv[4] = {t4.x, t4.y, t4.z, t4.w};
    int mv[4] = {m4.x, m4.y, m4.z, m4.w};

    unsigned key[4];
#pragma unroll
    for (int r = 0; r < 4; ++r) {
        unsigned u = __float_as_uint(pvals[r]);
        unsigned s = (u & 0x80000000u) ? ~u : (u | 0x80000000u);  // sortable asc
        unsigned label = (mv[r] == 1) ? (unsigned)tv[r] : 2u;     // 0,1,2
        key[r] = (s & ~3u) | label;
    }

    bitonic256_u32(key, lane);

    // packed per-element counts and inclusive prefix over sorted index
    unsigned c[4];
    int lab[4];
    float tval[4];
#pragma unroll
    for (int r = 0; r < 4; ++r) {
        lab[r] = (int)(key[r] & 3u);
        unsigned s = key[r] & ~3u;
        unsigned u = (s & 0x80000000u) ? (s ^ 0x80000000u) : ~s;
        tval[r] = __uint_as_float(u);
        c[r] = ((lab[r] == 0) ? 0x10000u : 0u) | ((lab[r] == 1) ? 1u : 0u);
#pragma unroll
        for (int d = 1; d < 64; d <<= 1) {
            unsigned t = (unsigned)__shfl_up((int)c[r], d, 64);
            if (lane >= d) c[r] += t;
        }
    }
    unsigned tot[4];
#pragma unroll
    for (int r = 0; r < 4; ++r) tot[r] = (unsigned)__shfl((int)c[r], 63, 64);
    unsigned total = tot[0] + tot[1] + tot[2] + tot[3];
    int n0 = (int)(total >> 16), n1 = (int)(total & 0xffffu);
    int m = (n0 < n1) ? n0 : n1;

    float ssum = 0.f;
    unsigned run = 0;
#pragma unroll
    for (int r = 0; r < 4; ++r) {
        unsigned C = c[r] + run;
        int c0 = (int)(C >> 16), c1 = (int)(C & 0xffffu);
        int s0 = (lab[r] == 0), s1 = (lab[r] == 1);
        int wi = abs(min(c0, m) - min(c1, m));
        int wp = abs(min(c0 - s0, m) - min(c1 - s1, m));
        ssum += tval[r] * (float)(wp - wi);
        run += tot[r];
    }
    for (int off = 32; off; off >>= 1) ssum += __shfl_xor(ssum, off, 64);
    if (lane == 0) dist[b * NPROJ_ + p] = ssum / (float)((m > 1) ? m : 1);
}

// ---------------------------------------------------------------------------
// Kernel E: max over p, layernorm, classifier (unchanged)
// ---------------------------------------------------------------------------
__global__ __launch_bounds__(64) void final_kernel(
    const float* __restrict__ fused, const float* __restrict__ dist,
    const float* __restrict__ ln_g, const float* __restrict__ ln_b,
    const float* __restrict__ Wcls, const float* __restrict__ bcls,
    float* __restrict__ out)
{
    int b = blockIdx.x;
    int lane = threadIdx.x;

    float mx = fmaxf(dist[b * NPROJ_ + lane], dist[b * NPROJ_ + 64 + lane]);
    for (int off = 32; off; off >>= 1) mx = fmaxf(mx, __shfl_xor(mx, off, 64));

    float fv[6];
    float sum = 0.f, sq = 0.f;
#pragma unroll
    for (int u = 0; u < 6; ++u) {
        int j = lane + u * 64;
        float x = 0.f;
        if (j < CDIM_ + SDIM_) x = fused[(size_t)b * (CDIM_ + SDIM_) + j];
        else if (j == CDIM_ + SDIM_) x = mx;
        fv[u] = x;
        if (j < FDIM_) { sum += x; sq += x * x; }
    }
    for (int off = 32; off; off >>= 1) {
        sum += __shfl_xor(sum, off, 64);
        sq  += __shfl_xor(sq,  off, 64);
    }
    float mu = sum / (float)FDIM_;
    float var = sq / (float)FDIM_ - mu * mu;
    float inv = rsqrtf(var + 1e-5f);

    float d0 = 0.f, d1 = 0.f;
#pragma unroll
    for (int u = 0; u < 6; ++u) {
        int j = lane + u * 64;
        if (j < FDIM_) {
            float nx = (fv[u] - mu) * inv * ln_g[j] + ln_b[j];
            d0 += nx * Wcls[j];
            d1 += nx * Wcls[FDIM_ + j];
        }
    }
    for (int off = 32; off; off >>= 1) {
        d0 += __shfl_xor(d0, off, 64);
        d1 += __shfl_xor(d1, off, 64);
    }
    if (lane == 0) {
        out[b * 2 + 0] = d0 + bcls[0];
        out[b * 2 + 1] = d1 + bcls[1];
    }
}

// ---------------------------------------------------------------------------
extern "C" void kernel_launch(void* const* d_in, const int* in_sizes, int n_in,
                              void* d_out, int out_size, void* d_ws, size_t ws_size,
                              hipStream_t stream)
{
    const float* H    = (const float*)d_in[0];
    const int*   tt   = (const int*)d_in[1];
    const int*   mm   = (const int*)d_in[2];
    const float* Wc   = (const float*)d_in[3];
    const float* bc   = (const float*)d_in[4];
    const float* Ws   = (const float*)d_in[5];
    const float* bs   = (const float*)d_in[6];
    const float* gate = (const float*)d_in[7];
    const float* ln_g = (const float*)d_in[8];
    const float* ln_b = (const float*)d_in[9];
    const float* Wcls = (const float*)d_in[10];
    const float* bcls = (const float*)d_in[11];
    const float* Pd   = (const float*)d_in[12];
    float* out = (float*)d_out;

    float* ws = (float*)d_ws;
    float* Pt    = ws;                                   // B*NPROJ*L floats
    float* part  = Pt;                                   // alias: consumed before Pt written
    float* rep   = Pt + (size_t)B_ * NPROJ_ * L_;
    float* fused = rep + (size_t)B_ * HID2_;
    float* dist  = fused + (size_t)B_ * (CDIM_ + SDIM_);
    unsigned short* Pjh = (unsigned short*)(dist + (size_t)B_ * NPROJ_);
    unsigned short* Pjl = Pjh + (size_t)NPROJ_ * HID_;

    conv_proj<<<NPROJ_ * HID_ / 4 / 256, 256, 0, stream>>>(Pd, Pjh, Pjl);
    stats_part<<<B_ * 4, 192, 0, stream>>>(H, tt, mm, part);
    stats_fin<<<B_, 256, 0, stream>>>(H, tt, mm, part, rep);
    head_kernel<<<B_ * (CDIM_ + SDIM_) / 4, 256, 0, stream>>>(rep, Wc, bc, Ws, bs, gate, fused);
    gemm_mfma<<<B_ * 4, 256, 0, stream>>>(H, Pjh, Pjl, Pt);   // overwrites part (safe: already consumed)
    ot_kernel<<<B_ * NPROJ_ / 4, 256, 0, stream>>>(Pt, tt, mm, dist);
    final_kernel<<<B_, 64, 0, stream>>>(fused, dist, ln_g, ln_b, Wcls, bcls, out);
}

// Round 4
// 252.781 us; speedup vs baseline: 1.6644x; 1.0498x over previous
//
#include <hip/hip_runtime.h>
#include <cmath>

#define B_   128
#define L_   256
#define HID_ 768
#define HID2_ 1536
#define CDIM_ 192
#define SDIM_ 128
#define NPROJ_ 128
#define FDIM_ 321

typedef __attribute__((ext_vector_type(8))) short bf16x8;
typedef __attribute__((ext_vector_type(4))) float f32x4;

__device__ inline unsigned short bf_hi_trunc(float x) {
    return (unsigned short)(__float_as_uint(x) >> 16);
}
__device__ inline float bf2f(unsigned short s) {
    return __uint_as_float(((unsigned int)s) << 16);
}
__device__ inline unsigned short f2bf_rne(float x) {
    unsigned int u = __float_as_uint(x);
    unsigned int r = (u + 0x7fff + ((u >> 16) & 1)) >> 16;
    return (unsigned short)r;
}

// ---------------------------------------------------------------------------
// Kernel A1: partial masked sums. grid = B*8, 192 threads, 32 l-rows each.
// part[(b*8+pr)][0:768]=sum f0*H, [768:1536]=sum f1*H
// ---------------------------------------------------------------------------
__global__ __launch_bounds__(192) void stats_part(
    const float* __restrict__ H, const int* __restrict__ tt,
    const int* __restrict__ mm, float* __restrict__ part)
{
    int b  = blockIdx.x >> 3;
    int pr = blockIdx.x & 7;
    int tid = threadIdx.x;

    __shared__ float sf0[32], sf1[32];
    if (tid < 32) {
        int l = pr * 32 + tid;
        int t = tt[b * L_ + l];
        int mv = mm[b * L_ + l];
        sf0[tid] = (t == 0 && mv == 1) ? 1.f : 0.f;
        sf1[tid] = (t == 1 && mv == 1) ? 1.f : 0.f;
    }
    __syncthreads();

    const float* Hb = H + ((size_t)(b * L_ + pr * 32)) * HID_;
    float4 a0 = make_float4(0.f, 0.f, 0.f, 0.f);
    float4 a1 = make_float4(0.f, 0.f, 0.f, 0.f);
    for (int l = 0; l < 32; ++l) {
        float4 x = *(const float4*)(Hb + (size_t)l * HID_ + tid * 4);
        float f0 = sf0[l], f1 = sf1[l];
        a0.x += x.x * f0; a0.y += x.y * f0; a0.z += x.z * f0; a0.w += x.w * f0;
        a1.x += x.x * f1; a1.y += x.y * f1; a1.z += x.z * f1; a1.w += x.w * f1;
    }
    float* dst = part + ((size_t)(b * 8 + pr)) * HID2_;
    *(float4*)(dst + tid * 4) = a0;
    *(float4*)(dst + HID_ + tid * 4) = a1;
}

// ---------------------------------------------------------------------------
// Kernel A2: finalize rep. grid = B, 256 threads.
// ---------------------------------------------------------------------------
__global__ __launch_bounds__(256) void stats_fin(
    const float* __restrict__ H, const int* __restrict__ tt,
    const int* __restrict__ mm, const float* __restrict__ part,
    float* __restrict__ rep)
{
    int b = blockIdx.x;
    int tid = threadIdx.x;
    int t = tt[b * L_ + tid];
    int mv = mm[b * L_ + tid];
    int n0 = __syncthreads_count(t == 0 && mv == 1);
    int n1 = __syncthreads_count(t == 1 && mv == 1);
    float r0 = 1.f / fmaxf((float)n0, 1.f);
    float r1 = 1.f / fmaxf((float)n1, 1.f);

    const float* pp = part + (size_t)b * 8 * HID2_;
    for (int h = tid; h < HID_; h += 256) {
        float a0 = 0.f, a1 = 0.f;
#pragma unroll
        for (int q = 0; q < 8; ++q) {
            a0 += pp[(size_t)q * HID2_ + h];
            a1 += pp[(size_t)q * HID2_ + HID_ + h];
        }
        rep[(size_t)b * HID2_ + h] = H[(size_t)b * L_ * HID_ + h];
        rep[(size_t)b * HID2_ + HID_ + h] = a0 * r0 - a1 * r1;
    }
}

// ---------------------------------------------------------------------------
// Kernel B: fused head (unchanged)
// ---------------------------------------------------------------------------
__global__ __launch_bounds__(256) void head_kernel(
    const float* __restrict__ rep, const float* __restrict__ Wc,
    const float* __restrict__ bc, const float* __restrict__ Ws,
    const float* __restrict__ bs, const float* __restrict__ gate,
    float* __restrict__ fused)
{
    int w = blockIdx.x * 4 + (threadIdx.x >> 6);
    int lane = threadIdx.x & 63;
    int b = w / (CDIM_ + SDIM_);
    int o = w % (CDIM_ + SDIM_);
    bool isC = (o < CDIM_);
    const float4* wr = (const float4*)(isC ? (Wc + (size_t)o * HID2_)
                                           : (Ws + (size_t)(o - CDIM_) * HID2_));
    const float4* rp = (const float4*)(rep + (size_t)b * HID2_);
    float acc = 0.f;
#pragma unroll
    for (int u = 0; u < 6; ++u) {
        int k4 = lane + u * 64;
        float4 a = rp[k4];
        float4 ww = wr[k4];
        acc += a.x * ww.x + a.y * ww.y + a.z * ww.z + a.w * ww.w;
    }
    for (int off = 32; off; off >>= 1) acc += __shfl_xor(acc, off, 64);
    if (lane == 0) {
        float g = 1.0f / (1.0f + expf(-gate[0]));
        float bias = isC ? bc[o] : bs[o - CDIM_];
        float scale = isC ? (1.0f - g) : g;
        fused[(size_t)b * (CDIM_ + SDIM_) + o] = (acc + bias) * scale;
    }
}

// ---------------------------------------------------------------------------
// Kernel C0: pre-convert proj_dirs to bf16 hi/lo (unchanged)
// ---------------------------------------------------------------------------
__global__ __launch_bounds__(256) void conv_proj(
    const float* __restrict__ Pd, unsigned short* __restrict__ hi,
    unsigned short* __restrict__ lo)
{
    int i = blockIdx.x * 256 + threadIdx.x;
    float4 v = ((const float4*)Pd)[i];
    ushort4 h, l;
    h.x = bf_hi_trunc(v.x); l.x = f2bf_rne(v.x - bf2f(h.x));
    h.y = bf_hi_trunc(v.y); l.y = f2bf_rne(v.y - bf2f(h.y));
    h.z = bf_hi_trunc(v.z); l.z = f2bf_rne(v.z - bf2f(h.z));
    h.w = bf_hi_trunc(v.w); l.w = f2bf_rne(v.w - bf2f(h.w));
    ((ushort4*)hi)[i] = h;
    ((ushort4*)lo)[i] = l;
}

// ---------------------------------------------------------------------------
// Kernel C: split-bf16 MFMA GEMM, LDS double-buffer (unchanged from R3)
// ---------------------------------------------------------------------------
#define LDSROW 72
__global__ __launch_bounds__(256) void gemm_mfma(
    const float* __restrict__ H, const unsigned short* __restrict__ Pjh,
    const unsigned short* __restrict__ Pjl, float* __restrict__ Pt)
{
    __shared__ unsigned short Ps[2][128 * LDSROW];
    __shared__ unsigned short Hs[2][64 * LDSROW];

    int tid = threadIdx.x;
    int w = tid >> 6;
    int lane = tid & 63;
    int c = lane & 15;
    int q = lane >> 4;

    int b = blockIdx.x >> 2;
    int lbase = (blockIdx.x & 3) * 64;

    const float* Hbase = H + ((size_t)(b * L_ + lbase)) * HID_;

    int hrow = tid >> 3;
    int hc4  = tid & 7;
    int prow = tid >> 2;
    int pk8  = tid & 3;

    f32x4 acc[2][4] = {};

    float4 hreg[2];
    uint4  phreg[2], plreg[2];

    hreg[0]  = *(const float4*)(Hbase + (size_t)hrow * HID_ + hc4 * 4);
    hreg[1]  = *(const float4*)(Hbase + (size_t)(hrow + 32) * HID_ + hc4 * 4);
    phreg[0] = *(const uint4*)(Pjh + (size_t)prow * HID_ + pk8 * 8);
    phreg[1] = *(const uint4*)(Pjh + (size_t)(prow + 64) * HID_ + pk8 * 8);
    plreg[0] = *(const uint4*)(Pjl + (size_t)prow * HID_ + pk8 * 8);
    plreg[1] = *(const uint4*)(Pjl + (size_t)(prow + 64) * HID_ + pk8 * 8);
#pragma unroll
    for (int u = 0; u < 2; ++u) {
        int row = hrow + u * 32;
        float4 v = hreg[u];
        ushort4 h, l;
        h.x = bf_hi_trunc(v.x); l.x = f2bf_rne(v.x - bf2f(h.x));
        h.y = bf_hi_trunc(v.y); l.y = f2bf_rne(v.y - bf2f(h.y));
        h.z = bf_hi_trunc(v.z); l.z = f2bf_rne(v.z - bf2f(h.z));
        h.w = bf_hi_trunc(v.w); l.w = f2bf_rne(v.w - bf2f(h.w));
        *(ushort4*)&Hs[0][row * LDSROW + hc4 * 4]      = h;
        *(ushort4*)&Hs[0][row * LDSROW + 32 + hc4 * 4] = l;
    }
#pragma unroll
    for (int u = 0; u < 2; ++u) {
        int row = prow + u * 64;
        *(uint4*)&Ps[0][row * LDSROW + pk8 * 8]      = phreg[u];
        *(uint4*)&Ps[0][row * LDSROW + 32 + pk8 * 8] = plreg[u];
    }
    __syncthreads();

    for (int it = 0; it < 24; ++it) {
        int cur = it & 1;
        int nxt = cur ^ 1;

        if (it + 1 < 24) {
            int k0 = (it + 1) * 32;
            hreg[0]  = *(const float4*)(Hbase + (size_t)hrow * HID_ + k0 + hc4 * 4);
            hreg[1]  = *(const float4*)(Hbase + (size_t)(hrow + 32) * HID_ + k0 + hc4 * 4);
            phreg[0] = *(const uint4*)(Pjh + (size_t)prow * HID_ + k0 + pk8 * 8);
            phreg[1] = *(const uint4*)(Pjh + (size_t)(prow + 64) * HID_ + k0 + pk8 * 8);
            plreg[0] = *(const uint4*)(Pjl + (size_t)prow * HID_ + k0 + pk8 * 8);
            plreg[1] = *(const uint4*)(Pjl + (size_t)(prow + 64) * HID_ + k0 + pk8 * 8);
        }

        bf16x8 ah[2], al[2], bh[4], bl[4];
#pragma unroll
        for (int pt = 0; pt < 2; ++pt) {
            int p = w * 32 + pt * 16 + c;
            ah[pt] = *(const bf16x8*)&Ps[cur][p * LDSROW + q * 8];
            al[pt] = *(const bf16x8*)&Ps[cur][p * LDSROW + 32 + q * 8];
        }
#pragma unroll
        for (int lt = 0; lt < 4; ++lt) {
            int l = lt * 16 + c;
            bh[lt] = *(const bf16x8*)&Hs[cur][l * LDSROW + q * 8];
            bl[lt] = *(const bf16x8*)&Hs[cur][l * LDSROW + 32 + q * 8];
        }
#pragma unroll
        for (int pt = 0; pt < 2; ++pt)
#pragma unroll
        for (int lt = 0; lt < 4; ++lt) {
            acc[pt][lt] = __builtin_amdgcn_mfma_f32_16x16x32_bf16(ah[pt], bh[lt], acc[pt][lt], 0, 0, 0);
            acc[pt][lt] = __builtin_amdgcn_mfma_f32_16x16x32_bf16(ah[pt], bl[lt], acc[pt][lt], 0, 0, 0);
            acc[pt][lt] = __builtin_amdgcn_mfma_f32_16x16x32_bf16(al[pt], bh[lt], acc[pt][lt], 0, 0, 0);
        }

        if (it + 1 < 24) {
#pragma unroll
            for (int u = 0; u < 2; ++u) {
                int row = hrow + u * 32;
                float4 v = hreg[u];
                ushort4 h, l;
                h.x = bf_hi_trunc(v.x); l.x = f2bf_rne(v.x - bf2f(h.x));
                h.y = bf_hi_trunc(v.y); l.y = f2bf_rne(v.y - bf2f(h.y));
                h.z = bf_hi_trunc(v.z); l.z = f2bf_rne(v.z - bf2f(h.z));
                h.w = bf_hi_trunc(v.w); l.w = f2bf_rne(v.w - bf2f(h.w));
                *(ushort4*)&Hs[nxt][row * LDSROW + hc4 * 4]      = h;
                *(ushort4*)&Hs[nxt][row * LDSROW + 32 + hc4 * 4] = l;
            }
#pragma unroll
            for (int u = 0; u < 2; ++u) {
                int row = prow + u * 64;
                *(uint4*)&Ps[nxt][row * LDSROW + pk8 * 8]      = phreg[u];
                *(uint4*)&Ps[nxt][row * LDSROW + 32 + pk8 * 8] = plreg[u];
            }
        }
        __syncthreads();
    }

#pragma unroll
    for (int pt = 0; pt < 2; ++pt)
#pragma unroll
    for (int lt = 0; lt < 4; ++lt)
#pragma unroll
    for (int r = 0; r < 4; ++r) {
        int p = w * 32 + pt * 16 + q * 4 + r;
        int l = lbase + lt * 16 + c;
        Pt[((size_t)(b * NPROJ_ + p)) * L_ + l] = acc[pt][lt][r];
    }
}

// ---------------------------------------------------------------------------
// Kernel D: merged-sort W1 distance, contiguous-element bitonic layout.
// element i = 4*lane + r  (matches float4 load order). j<4 stages in-register.
// ---------------------------------------------------------------------------
__global__ __launch_bounds__(256) void ot_kernel(
    const float* __restrict__ Pt, const int* __restrict__ tt,
    const int* __restrict__ mm, float* __restrict__ dist)
{
    int w = blockIdx.x * 4 + (threadIdx.x >> 6);
    int lane = threadIdx.x & 63;
    int b = w >> 7;
    int p = w & (NPROJ_ - 1);

    float4 pv = *(const float4*)(Pt + ((size_t)(b * NPROJ_ + p)) * L_ + lane * 4);
    int4 t4 = *(const int4*)(tt + (size_t)b * L_ + lane * 4);
    int4 m4 = *(const int4*)(mm + (size_t)b * L_ + lane * 4);

    float pvals[4] = {pv.x, pv.y, pv.z, pv.w};
    int tv[4] = {t4.x, t4.y, t4.z, t4.w};
    int mv[4] = {m4.x, m4.y, m4.z, m4.w};

    unsigned key[4];
#pragma unroll
    for (int r = 0; r < 4; ++r) {
        unsigned u = __float_as_uint(pvals[r]);
        unsigned s = (u & 0x80000000u) ? ~u : (u | 0x80000000u);  // sortable asc
        unsigned label = (mv[r] == 1) ? (unsigned)tv[r] : 2u;     // 0,1,2
        key[r] = (s & ~3u) | label;
    }

    // ---- bitonic sort over i = 4*lane + r ----
    {   // k=2, j=1: dir = (i&2): regs (0,1) asc, (2,3) desc — fully static
        unsigned mn0 = min(key[0], key[1]), mx0 = max(key[0], key[1]);
        key[0] = mn0; key[1] = mx0;
        unsigned mn1 = min(key[2], key[3]), mx1 = max(key[2], key[3]);
        key[2] = mx1; key[3] = mn1;
    }
#pragma unroll
    for (int k = 4; k <= 256; k <<= 1) {
        bool up = (lane & (k >> 2)) == 0;   // (i & k) == 0
#pragma unroll
        for (int j = k >> 1; j >= 4; j >>= 1) {
            int lj = j >> 2;
            bool lower_eq_up;
            {
                // lower = (lane & lj)==0 ; keep min iff lower==up
            }
#pragma unroll
            for (int r = 0; r < 4; ++r) {
                unsigned o = (unsigned)__shfl_xor((int)key[r], lj, 64);
                bool lower = (lane & lj) == 0;
                unsigned mn = min(key[r], o), mx = max(key[r], o);
                key[r] = (lower == up) ? mn : mx;
            }
        }
        {   // j=2: pairs (0,2),(1,3)
            unsigned mn0 = min(key[0], key[2]), mx0 = max(key[0], key[2]);
            key[0] = up ? mn0 : mx0; key[2] = up ? mx0 : mn0;
            unsigned mn1 = min(key[1], key[3]), mx1 = max(key[1], key[3]);
            key[1] = up ? mn1 : mx1; key[3] = up ? mx1 : mn1;
        }
        {   // j=1: pairs (0,1),(2,3)
            unsigned mn0 = min(key[0], key[1]), mx0 = max(key[0], key[1]);
            key[0] = up ? mn0 : mx0; key[1] = up ? mx0 : mn0;
            unsigned mn1 = min(key[2], key[3]), mx1 = max(key[2], key[3]);
            key[2] = up ? mn1 : mx1; key[3] = up ? mx1 : mn1;
        }
    }

    // ---- decode + single packed scan over rank i = 4*lane + r ----
    int lab[4];
    float tval[4];
    unsigned sincl[4];
    unsigned run = 0;
#pragma unroll
    for (int r = 0; r < 4; ++r) {
        lab[r] = (int)(key[r] & 3u);
        unsigned s = key[r] & ~3u;
        unsigned u = (s & 0x80000000u) ? (s ^ 0x80000000u) : ~s;
        tval[r] = __uint_as_float(u);
        unsigned unit = ((lab[r] == 0) ? 0x10000u : 0u) | ((lab[r] == 1) ? 1u : 0u);
        run += unit;
        sincl[r] = run;   // lane-local inclusive
    }
    unsigned inc = run;   // lane total
#pragma unroll
    for (int d = 1; d < 64; d <<= 1) {
        unsigned t = (unsigned)__shfl_up((int)inc, d, 64);
        if (lane >= d) inc += t;
    }
    unsigned ex = inc - run;                       // exclusive lane prefix
    unsigned total = (unsigned)__shfl((int)inc, 63, 64);
    int n0 = (int)(total >> 16), n1 = (int)(total & 0xffffu);
    int m = (n0 < n1) ? n0 : n1;

    float ssum = 0.f;
#pragma unroll
    for (int r = 0; r < 4; ++r) {
        unsigned C = ex + sincl[r];                // global inclusive count
        int c0 = (int)(C >> 16), c1 = (int)(C & 0xffffu);
        int s0 = (lab[r] == 0), s1 = (lab[r] == 1);
        int wi = abs(min(c0, m) - min(c1, m));
        int wp = abs(min(c0 - s0, m) - min(c1 - s1, m));
        ssum += tval[r] * (float)(wp - wi);
    }
    for (int off = 32; off; off >>= 1) ssum += __shfl_xor(ssum, off, 64);
    if (lane == 0) dist[b * NPROJ_ + p] = ssum / (float)((m > 1) ? m : 1);
}

// ---------------------------------------------------------------------------
// Kernel E: max over p, layernorm, classifier (unchanged)
// ---------------------------------------------------------------------------
__global__ __launch_bounds__(64) void final_kernel(
    const float* __restrict__ fused, const float* __restrict__ dist,
    const float* __restrict__ ln_g, const float* __restrict__ ln_b,
    const float* __restrict__ Wcls, const float* __restrict__ bcls,
    float* __restrict__ out)
{
    int b = blockIdx.x;
    int lane = threadIdx.x;

    float mx = fmaxf(dist[b * NPROJ_ + lane], dist[b * NPROJ_ + 64 + lane]);
    for (int off = 32; off; off >>= 1) mx = fmaxf(mx, __shfl_xor(mx, off, 64));

    float fv[6];
    float sum = 0.f, sq = 0.f;
#pragma unroll
    for (int u = 0; u < 6; ++u) {
        int j = lane + u * 64;
        float x = 0.f;
        if (j < CDIM_ + SDIM_) x = fused[(size_t)b * (CDIM_ + SDIM_) + j];
        else if (j == CDIM_ + SDIM_) x = mx;
        fv[u] = x;
        if (j < FDIM_) { sum += x; sq += x * x; }
    }
    for (int off = 32; off; off >>= 1) {
        sum += __shfl_xor(sum, off, 64);
        sq  += __shfl_xor(sq,  off, 64);
    }
    float mu = sum / (float)FDIM_;
    float var = sq / (float)FDIM_ - mu * mu;
    float inv = rsqrtf(var + 1e-5f);

    float d0 = 0.f, d1 = 0.f;
#pragma unroll
    for (int u = 0; u < 6; ++u) {
        int j = lane + u * 64;
        if (j < FDIM_) {
            float nx = (fv[u] - mu) * inv * ln_g[j] + ln_b[j];
            d0 += nx * Wcls[j];
            d1 += nx * Wcls[FDIM_ + j];
        }
    }
    for (int off = 32; off; off >>= 1) {
        d0 += __shfl_xor(d0, off, 64);
        d1 += __shfl_xor(d1, off, 64);
    }
    if (lane == 0) {
        out[b * 2 + 0] = d0 + bcls[0];
        out[b * 2 + 1] = d1 + bcls[1];
    }
}

// ---------------------------------------------------------------------------
extern "C" void kernel_launch(void* const* d_in, const int* in_sizes, int n_in,
                              void* d_out, int out_size, void* d_ws, size_t ws_size,
                              hipStream_t stream)
{
    const float* H    = (const float*)d_in[0];
    const int*   tt   = (const int*)d_in[1];
    const int*   mm   = (const int*)d_in[2];
    const float* Wc   = (const float*)d_in[3];
    const float* bc   = (const float*)d_in[4];
    const float* Ws   = (const float*)d_in[5];
    const float* bs   = (const float*)d_in[6];
    const float* gate = (const float*)d_in[7];
    const float* ln_g = (const float*)d_in[8];
    const float* ln_b = (const float*)d_in[9];
    const float* Wcls = (const float*)d_in[10];
    const float* bcls = (const float*)d_in[11];
    const float* Pd   = (const float*)d_in[12];
    float* out = (float*)d_out;

    float* ws = (float*)d_ws;
    float* Pt    = ws;                                   // B*NPROJ*L floats
    float* part  = Pt;                                   // alias: consumed before Pt written
    float* rep   = Pt + (size_t)B_ * NPROJ_ * L_;
    float* fused = rep + (size_t)B_ * HID2_;
    float* dist  = fused + (size_t)B_ * (CDIM_ + SDIM_);
    unsigned short* Pjh = (unsigned short*)(dist + (size_t)B_ * NPROJ_);
    unsigned short* Pjl = Pjh + (size_t)NPROJ_ * HID_;

    conv_proj<<<NPROJ_ * HID_ / 4 / 256, 256, 0, stream>>>(Pd, Pjh, Pjl);
    stats_part<<<B_ * 8, 192, 0, stream>>>(H, tt, mm, part);
    stats_fin<<<B_, 256, 0, stream>>>(H, tt, mm, part, rep);
    head_kernel<<<B_ * (CDIM_ + SDIM_) / 4, 256, 0, stream>>>(rep, Wc, bc, Ws, bs, gate, fused);
    gemm_mfma<<<B_ * 4, 256, 0, stream>>>(H, Pjh, Pjl, Pt);   // overwrites part (safe)
    ot_kernel<<<B_ * NPROJ_ / 4, 256, 0, stream>>>(Pt, tt, mm, dist);
    final_kernel<<<B_, 64, 0, stream>>>(fused, dist, ln_g, ln_b, Wcls, bcls, out);
}